// Round 2
// baseline (6242.294 us; speedup 1.0000x reference)
//
#include <hip/hip_runtime.h>

typedef unsigned short u16;
typedef __attribute__((ext_vector_type(8))) short short8;
typedef __attribute__((ext_vector_type(4))) float f32x4;

#define DEV __device__ __forceinline__

// B=192, T=64, ACT=16, EMB=1024, STOCH=32, DETER=600, HID=600
// out row stride = 1392: [mean_po 0, std_po 32, stoch_po 64, deter 96,
//                         mean_pr 696, std_pr 728, stoch_pr 760, deter 792]
// xd row stride = 1280: [x 0..599, deter 600..1199, zero pad 1200..1279]
#define XDS 1280

DEV u16 f2bf(float f) {
  unsigned u = __float_as_uint(f);
  u = (u + 0x7FFFu + ((u >> 16) & 1u)) >> 16;
  return (u16)u;
}
DEV float bf2f(u16 h) { return __uint_as_float(((unsigned)h) << 16); }
DEV float sigf(float x) { return 1.f / (1.f + __expf(-x)); }
DEV float eluf(float x) { return x > 0.f ? x : __expf(x) - 1.f; }

// ---------------- conversion with zero row padding ----------------
__global__ __launch_bounds__(256) void conv_pad(const float* __restrict__ src,
                                                u16* __restrict__ dst,
                                                int K, int N, int Kpad, int srcRowOff) {
  size_t total = (size_t)Kpad * N;
  for (size_t idx = (size_t)blockIdx.x * 256 + threadIdx.x; idx < total;
       idx += (size_t)gridDim.x * 256) {
    int k = (int)(idx / (size_t)N);
    int n = (int)(idx % (size_t)N);
    dst[idx] = (k < K) ? f2bf(src[(size_t)(k + srcRowOff) * N + n]) : (u16)0;
  }
}

// ---------------- MFMA 64x64 tile core ----------------
DEV void mfma_tile(const u16 (*As)[72], const u16 (*Bs)[72], int wm, int wn,
                   int lane, f32x4 acc[2][2]) {
#pragma unroll
  for (int s = 0; s < 2; ++s) {
    const int ko = s * 32 + ((lane >> 4) << 3);
    short8 a0 = *reinterpret_cast<const short8*>(&As[wm + (lane & 15)][ko]);
    short8 a1 = *reinterpret_cast<const short8*>(&As[wm + 16 + (lane & 15)][ko]);
    short8 b0 = *reinterpret_cast<const short8*>(&Bs[wn + (lane & 15)][ko]);
    short8 b1 = *reinterpret_cast<const short8*>(&Bs[wn + 16 + (lane & 15)][ko]);
    acc[0][0] = __builtin_amdgcn_mfma_f32_16x16x32_bf16(a0, b0, acc[0][0], 0, 0, 0);
    acc[0][1] = __builtin_amdgcn_mfma_f32_16x16x32_bf16(a0, b1, acc[0][1], 0, 0, 0);
    acc[1][0] = __builtin_amdgcn_mfma_f32_16x16x32_bf16(a1, b0, acc[1][0], 0, 0, 0);
    acc[1][1] = __builtin_amdgcn_mfma_f32_16x16x32_bf16(a1, b1, acc[1][1], 0, 0, 0);
  }
}

// ---------------- generic 64x64-tiled bf16 GEMM ----------------
// EPI: 0 = +bias, f32 out ; 1 = +bias, bf16 out ; 2 = +bias, elu, bf16 out ;
//      3 = +addm(bf16 matrix), elu, bf16 out
template <int EPI>
__global__ __launch_bounds__(256) void gemm64(
    const u16* __restrict__ A, int lda, const u16* __restrict__ W, int ldw,
    const float* __restrict__ bias, const u16* __restrict__ addm, int ldadd,
    void* __restrict__ Cv, int ldc, int Nstore, int N, int K) {
  __shared__ u16 As[64][72];
  __shared__ u16 Bs[64][72];
  const int tid = threadIdx.x, lane = tid & 63, wave = tid >> 6;
  const int wm = (wave & 1) * 32, wn = (wave >> 1) * 32;
  const int bn0 = blockIdx.x * 64, bm0 = blockIdx.y * 64;
  const int am = tid >> 2, ak0 = (tid & 3) * 16;
  const int bk = tid >> 3, bn = (tid & 7) * 8;

  f32x4 acc[2][2] = {};
  for (int k0 = 0; k0 < K; k0 += 64) {
    __syncthreads();
    {
      const u16* src = A + (size_t)(bm0 + am) * lda + k0 + ak0;
      *reinterpret_cast<short8*>(&As[am][ak0]) = *reinterpret_cast<const short8*>(src);
      *reinterpret_cast<short8*>(&As[am][ak0 + 8]) = *reinterpret_cast<const short8*>(src + 8);
    }
    {
      int gn = bn0 + bn;
#pragma unroll
      for (int h = 0; h < 2; ++h) {
        int kk = k0 + bk + h * 32;
        short8 v;
        if (gn + 7 < N) {
          v = *reinterpret_cast<const short8*>(W + (size_t)kk * ldw + gn);
        } else {
          for (int j = 0; j < 8; ++j)
            v[j] = (gn + j < N) ? (short)W[(size_t)kk * ldw + gn + j] : (short)0;
        }
#pragma unroll
        for (int j = 0; j < 8; ++j) Bs[bn + j][bk + h * 32] = (u16)v[j];
      }
    }
    __syncthreads();
    mfma_tile(As, Bs, wm, wn, lane, acc);
  }

#pragma unroll
  for (int r = 0; r < 2; ++r)
#pragma unroll
    for (int c = 0; c < 2; ++c)
#pragma unroll
      for (int i = 0; i < 4; ++i) {
        int grow = bm0 + wm + r * 16 + ((lane >> 4) << 2) + i;
        int gcol = bn0 + wn + c * 16 + (lane & 15);
        if (gcol >= Nstore) continue;
        bool ok = gcol < N;
        float v = acc[r][c][i];
        if (EPI == 3)
          v += ok ? bf2f(addm[(size_t)grow * ldadd + gcol]) : 0.f;
        else
          v += ok ? bias[gcol] : 0.f;
        if (EPI >= 2) v = eluf(v);
        if (EPI == 0)
          ((float*)Cv)[(size_t)grow * ldc + gcol] = ok ? v : 0.f;
        else
          ((u16*)Cv)[(size_t)grow * ldc + gcol] = ok ? f2bf(v) : (u16)0;
      }
}

// ---------------- init: x(t=0) = elu(action-part), deter = 0, pads = 0 -------
__global__ __launch_bounds__(256) void k_init(const float* __restrict__ action,
                                              const float* __restrict__ img1w,
                                              const float* __restrict__ img1b,
                                              float* __restrict__ df32,
                                              u16* __restrict__ xd) {
  __shared__ float act[16];
  int b = blockIdx.x, tid = threadIdx.x;
  if (tid < 16) act[tid] = action[(size_t)b * 64 * 16 + tid];  // t = 0
  __syncthreads();
  for (int h = tid; h < 600; h += 256) {
    float s = img1b[h];
#pragma unroll
    for (int a = 0; a < 16; ++a) s += act[a] * img1w[(size_t)(32 + a) * 600 + h];
    xd[(size_t)b * XDS + h] = f2bf(eluf(s));
  }
  for (int j = tid; j < 680; j += 256) xd[(size_t)b * XDS + 600 + j] = 0;
  for (int j = tid; j < 600; j += 256) df32[(size_t)b * 600 + j] = 0.f;
}

// ---------------- LN + GRU gates ----------------
__global__ __launch_bounds__(256) void k_ln(const float* __restrict__ parts,
                                            const float* __restrict__ lns,
                                            const float* __restrict__ lnb,
                                            float* __restrict__ dprev,
                                            u16* __restrict__ xd,
                                            u16* __restrict__ dall,
                                            float* __restrict__ out, int t) {
  __shared__ float pl[1800];
  __shared__ float red[256];
  int b = blockIdx.x, tid = threadIdx.x;
  float s = 0.f;
  for (int i = tid; i < 1800; i += 256) {
    float v = parts[(size_t)b * 1800 + i];
    pl[i] = v;
    s += v;
  }
  red[tid] = s;
  __syncthreads();
  for (int o = 128; o > 0; o >>= 1) {
    if (tid < o) red[tid] += red[tid + o];
    __syncthreads();
  }
  float m = red[0] * (1.f / 1800.f);
  __syncthreads();
  float q = 0.f;
  for (int i = tid; i < 1800; i += 256) {
    float d = pl[i] - m;
    q += d * d;
  }
  red[tid] = q;
  __syncthreads();
  for (int o = 128; o > 0; o >>= 1) {
    if (tid < o) red[tid] += red[tid + o];
    __syncthreads();
  }
  float rstd = rsqrtf(red[0] * (1.f / 1800.f) + 1e-5f);
  size_t orow = (size_t)b * 64 + t;
  for (int j = tid; j < 600; j += 256) {
    float p0 = (pl[j] - m) * rstd * lns[j] + lnb[j];
    float p1 = (pl[600 + j] - m) * rstd * lns[600 + j] + lnb[600 + j];
    float p2 = (pl[1200 + j] - m) * rstd * lns[1200 + j] + lnb[1200 + j];
    float r = sigf(p0);
    float cd = tanhf(r * p1);
    float u = sigf(p2 - 1.f);
    float dn = u * cd + (1.f - u) * dprev[(size_t)b * 600 + j];
    dprev[(size_t)b * 600 + j] = dn;
    xd[(size_t)b * XDS + 600 + j] = f2bf(dn);
    dall[orow * 640 + j] = f2bf(dn);
    out[orow * 1392 + 96 + j] = dn;
    out[orow * 1392 + 792 + j] = dn;
  }
  for (int j = tid; j < 40; j += 256) dall[orow * 640 + 600 + j] = 0;
}

// ---------------- head (N=64) GEMM + dist outputs (+ x-GEMM for posterior) ----
// OBS=1: per-step posterior (out base 0, noise_post, computes next x into xd)
// OBS=0: batched prior (out base 696, noise_prior)
template <int OBS>
__global__ __launch_bounds__(256) void head64(
    const u16* __restrict__ A, int lda, int K, const u16* __restrict__ W,
    const float* __restrict__ bias64, const float* __restrict__ noise,
    const float* __restrict__ action, const float* __restrict__ img1b,
    const u16* __restrict__ W1pad, u16* __restrict__ xd,
    float* __restrict__ out, int t) {
  __shared__ u16 As[64][72];
  __shared__ u16 Bs[64][72];
  __shared__ float sl[64][68];
  __shared__ u16 xa[64][72];
  const int tid = threadIdx.x, lane = tid & 63, wave = tid >> 6;
  const int wm = (wave & 1) * 32, wn = (wave >> 1) * 32;
  const int bm0 = blockIdx.x * 64;
  const int am = tid >> 2, ak0 = (tid & 3) * 16;
  const int bk = tid >> 3, bn = (tid & 7) * 8;

  f32x4 acc[2][2] = {};
  for (int k0 = 0; k0 < K; k0 += 64) {
    __syncthreads();
    {
      const u16* src = A + (size_t)(bm0 + am) * lda + k0 + ak0;
      *reinterpret_cast<short8*>(&As[am][ak0]) = *reinterpret_cast<const short8*>(src);
      *reinterpret_cast<short8*>(&As[am][ak0 + 8]) = *reinterpret_cast<const short8*>(src + 8);
    }
#pragma unroll
    for (int h = 0; h < 2; ++h) {
      int kk = k0 + bk + h * 32;
      short8 v = *reinterpret_cast<const short8*>(W + (size_t)kk * 64 + bn);
#pragma unroll
      for (int j = 0; j < 8; ++j) Bs[bn + j][bk + h * 32] = (u16)v[j];
    }
    __syncthreads();
    mfma_tile(As, Bs, wm, wn, lane, acc);
  }

#pragma unroll
  for (int r = 0; r < 2; ++r)
#pragma unroll
    for (int c = 0; c < 2; ++c)
#pragma unroll
      for (int i = 0; i < 4; ++i) {
        int col = wn + c * 16 + (lane & 15);
        sl[wm + r * 16 + ((lane >> 4) << 2) + i][col] = acc[r][c][i] + bias64[col];
      }
  __syncthreads();

  for (int task = tid; task < 64 * 32; task += 256) {
    int r = task >> 5, j = task & 31;
    int grow = bm0 + r;
    size_t orow = OBS ? ((size_t)grow * 64 + t) : (size_t)grow;
    size_t base = orow * 1392 + (OBS ? 0 : 696);
    float mean = sl[r][j];
    float sraw = sl[r][32 + j];
    float sd = 2.f * sigf(0.5f * sraw) + 0.1f;
    float st = mean + sd * noise[orow * 32 + j];
    out[base + j] = mean;
    out[base + 32 + j] = sd;
    out[base + 64 + j] = st;
    if (OBS) xa[r][j] = f2bf(st);
  }

  if (OBS) {
    if (t >= 63) return;  // uniform across block
    for (int task = tid; task < 64 * 16; task += 256) {
      int r = task >> 4, a2 = task & 15;
      xa[r][32 + a2] = f2bf(action[((size_t)(bm0 + r) * 64 + (t + 1)) * 16 + a2]);
      xa[r][48 + a2] = 0;
    }
    __syncthreads();
    for (int ct = 0; ct < 10; ++ct) {
      __syncthreads();
      for (int idx = tid; idx < 512; idx += 256) {
        int k = idx >> 3, n0 = (idx & 7) * 8;
        int gn = ct * 64 + n0;
        short8 v;
        if (gn + 7 < 600) {
          v = *reinterpret_cast<const short8*>(W1pad + (size_t)k * 600 + gn);
        } else {
          for (int j = 0; j < 8; ++j)
            v[j] = (gn + j < 600) ? (short)W1pad[(size_t)k * 600 + gn + j] : (short)0;
        }
#pragma unroll
        for (int j = 0; j < 8; ++j) Bs[n0 + j][k] = (u16)v[j];
      }
      __syncthreads();
      f32x4 a2c[2][2] = {};
      mfma_tile(xa, Bs, wm, wn, lane, a2c);
#pragma unroll
      for (int r = 0; r < 2; ++r)
#pragma unroll
        for (int c = 0; c < 2; ++c)
#pragma unroll
          for (int i = 0; i < 4; ++i) {
            int grow = bm0 + wm + r * 16 + ((lane >> 4) << 2) + i;
            int gcol = ct * 64 + wn + c * 16 + (lane & 15);
            if (gcol < 600) {
              float v = eluf(a2c[r][c][i] + img1b[gcol]);
              xd[(size_t)grow * XDS + gcol] = f2bf(v);
            }
          }
    }
  }
}

// ---------------- launch ----------------
extern "C" void kernel_launch(void* const* d_in, const int* in_sizes, int n_in,
                              void* d_out, int out_size, void* d_ws, size_t ws_size,
                              hipStream_t stream) {
  (void)in_sizes; (void)n_in; (void)out_size; (void)ws_size;
  const float* action = (const float*)d_in[0];
  const float* embed = (const float*)d_in[1];
  const float* npr = (const float*)d_in[2];
  const float* npo = (const float*)d_in[3];
  const float* img1w = (const float*)d_in[4];
  const float* img1b = (const float*)d_in[5];
  const float* gruw = (const float*)d_in[6];
  const float* grub = (const float*)d_in[7];
  const float* lns = (const float*)d_in[8];
  const float* lnb = (const float*)d_in[9];
  const float* img2w = (const float*)d_in[10];
  const float* img2b = (const float*)d_in[11];
  const float* img3w = (const float*)d_in[12];
  const float* img3b = (const float*)d_in[13];
  const float* obs1w = (const float*)d_in[14];
  const float* obs1b = (const float*)d_in[15];
  const float* obs2w = (const float*)d_in[16];
  const float* obs2b = (const float*)d_in[17];
  float* out = (float*)d_out;
  char* ws = (char*)d_ws;

  size_t off = 0;
  auto alloc = [&](size_t bytes) {
    size_t o = off;
    off += (bytes + 255) & ~(size_t)255;
    return o;
  };
  size_t o_embed = alloc(12288ull * 1024 * 2);  // reused as dall (12288x640 bf16)
  size_t o_epre = alloc(12288ull * 600 * 2);    // reused (with o_wemb) as h_img
  size_t o_wemb = alloc(1024ull * 600 * 2);
  size_t o_gruw = alloc(1216ull * 1800 * 2);
  size_t o_o1w = alloc(640ull * 600 * 2);
  size_t o_i2w = alloc(640ull * 600 * 2);
  size_t o_i3w = alloc(640ull * 64 * 2);
  size_t o_o2w = alloc(640ull * 64 * 2);
  size_t o_w1p = alloc(64ull * 600 * 2);
  size_t o_xd = alloc(192ull * XDS * 2);
  size_t o_parts = alloc(192ull * 1800 * 4);
  size_t o_df32 = alloc(192ull * 600 * 4);
  size_t o_hobs = alloc(192ull * 640 * 2);

  u16* embed_bf = (u16*)(ws + o_embed);
  u16* dall = (u16*)(ws + o_embed);
  u16* epre = (u16*)(ws + o_epre);
  u16* himg = (u16*)(ws + o_epre);
  u16* wemb = (u16*)(ws + o_wemb);
  u16* gruwb = (u16*)(ws + o_gruw);
  u16* o1wb = (u16*)(ws + o_o1w);
  u16* i2wb = (u16*)(ws + o_i2w);
  u16* i3wb = (u16*)(ws + o_i3w);
  u16* o2wb = (u16*)(ws + o_o2w);
  u16* w1p = (u16*)(ws + o_w1p);
  u16* xd = (u16*)(ws + o_xd);
  float* parts = (float*)(ws + o_parts);
  float* df32 = (float*)(ws + o_df32);
  u16* hobs = (u16*)(ws + o_hobs);

  auto cg = [](size_t total) {
    size_t g = (total + 255) / 256;
    return (unsigned)(g > 4096 ? 4096 : g);
  };

  conv_pad<<<cg(12288ull * 1024), 256, 0, stream>>>(embed, embed_bf, 12288, 1024, 12288, 0);
  conv_pad<<<cg(1216ull * 1800), 256, 0, stream>>>(gruw, gruwb, 1200, 1800, 1216, 0);
  conv_pad<<<cg(1024ull * 600), 256, 0, stream>>>(obs1w, wemb, 1024, 600, 1024, 600);
  conv_pad<<<cg(640ull * 600), 256, 0, stream>>>(obs1w, o1wb, 600, 600, 640, 0);
  conv_pad<<<cg(640ull * 600), 256, 0, stream>>>(img2w, i2wb, 600, 600, 640, 0);
  conv_pad<<<cg(640ull * 64), 256, 0, stream>>>(img3w, i3wb, 600, 64, 640, 0);
  conv_pad<<<cg(640ull * 64), 256, 0, stream>>>(obs2w, o2wb, 600, 64, 640, 0);
  conv_pad<<<cg(64ull * 600), 256, 0, stream>>>(img1w, w1p, 48, 600, 64, 0);

  k_init<<<192, 256, 0, stream>>>(action, img1w, img1b, df32, xd);

  // epre[b*64+t][h] = embed @ obs1_w[600:,:] + obs1_b   (bf16 out)
  gemm64<1><<<dim3(10, 192), 256, 0, stream>>>(embed_bf, 1024, wemb, 600, obs1b,
                                               nullptr, 0, epre, 600, 600, 600, 1024);

  for (int t = 0; t < 64; ++t) {
    // parts = [x, deter] @ gru_w + gru_b   (f32 out)
    gemm64<0><<<dim3(29, 3), 256, 0, stream>>>(xd, XDS, gruwb, 1800, grub, nullptr, 0,
                                               parts, 1800, 1800, 1800, 1216);
    k_ln<<<192, 256, 0, stream>>>(parts, lns, lnb, df32, xd, dall, out, t);
    // h_obs = elu(deter_n @ obs1_w[:600] + epre)   (bf16 out, zero-padded to 640)
    gemm64<3><<<dim3(10, 3), 256, 0, stream>>>(xd + 600, XDS, o1wb, 600, nullptr,
                                               epre + (size_t)t * 600, 38400, hobs, 640,
                                               640, 600, 640);
    // posterior outputs + stoch + next x
    head64<1><<<3, 256, 0, stream>>>(hobs, 640, 640, o2wb, obs2b, npo, action, img1b,
                                     w1p, xd, out, t);
  }

  // batched prior: h_img = elu(deter_all @ img2_w + img2_b), then img3 head
  gemm64<2><<<dim3(10, 192), 256, 0, stream>>>(dall, 640, i2wb, 600, img2b, nullptr, 0,
                                               himg, 640, 640, 600, 640);
  head64<0><<<192, 256, 0, stream>>>(himg, 640, 640, i3wb, img3b, npr, nullptr, nullptr,
                                     nullptr, nullptr, out, -1);
}